// Round 12
// baseline (36.727 us; speedup 1.0000x reference)
//
#include <hip/hip_runtime.h>
#include <hip/hip_bf16.h>
#include <stdint.h>

// LogLinearCDE: out = softmax(W_out @ (y0 * prod_l flows[l]) + b_out)
// flows[l,h] = 1 + sum_c logsigs[l,c]*vf_A[c,h];  y0 = W_in@x0 + b_in
// R12: 3 kernels. (1) pack vf_A->bf16 hi/lo + zero logits/counter.
// (2) MFMA partial products (exact R9 kernel). (3) tailAB: per-h chunk
// product + y0 + per-block logits accumulated via device-scope atomicAdd
// (coherent across XCDs, no threadfence/L2-writeback), last block does
// softmax. Ordering: __syncthreads() drains vmcnt => adds complete before
// the counter bump.

#define LSTEPS 16384
#define HID    4096
#define CC     17
#define NLAB   10
#define NW     16          // packed u32 words per col (K padded to 32 bf16)
#define NCHUNK 256
#define CR     64          // rows per chunk
#define APAD   20          // LDS A row stride in words (80B, 16B-aligned)
#define HPB    16          // h per tail block
#define RBLK   256         // tail blocks

typedef __attribute__((ext_vector_type(8))) short short8;
typedef __attribute__((ext_vector_type(4))) float f32x4;

static __device__ __forceinline__ unsigned short f2bf(float x) {
  __hip_bfloat16 h = __float2bfloat16(x);
  return *reinterpret_cast<unsigned short*>(&h);
}
static __device__ __forceinline__ float bf2f(unsigned short u) {
  __hip_bfloat16 h; *reinterpret_cast<unsigned short*>(&h) = u;
  return __bfloat162float(h);
}
static __device__ __forceinline__ uint32_t pack_hi(float v0, float v1) {
  return (uint32_t)f2bf(v0) | ((uint32_t)f2bf(v1) << 16);
}
static __device__ __forceinline__ uint32_t pack_lo(float v0, float v1) {
  float r0 = v0 - bf2f(f2bf(v0)), r1 = v1 - bf2f(f2bf(v1));
  return (uint32_t)f2bf(r0) | ((uint32_t)f2bf(r1) << 16);
}

// pre-pass: pack vf_A (C,H) into per-column bf16 hi/lo K-words; zero
// the logit accumulator and counter (visible to later kernels via the
// kernel-boundary coherence flush).
__global__ __launch_bounds__(256) void pack_vfA_kernel(
    const float* __restrict__ vfA,
    uint32_t* __restrict__ pBh, uint32_t* __restrict__ pBl,
    float* __restrict__ ws_logit, uint32_t* __restrict__ cnt) {
  if (blockIdx.x == 0) {
    if (threadIdx.x < NLAB) ws_logit[threadIdx.x] = 0.0f;
    if (threadIdx.x == NLAB) *cnt = 0u;
  }
  const int c = blockIdx.x*256 + threadIdx.x;
  float v[2*NW];
  #pragma unroll
  for (int k = 0; k < 2*NW; ++k) v[k] = (k < CC) ? vfA[k*HID + c] : 0.0f;
  #pragma unroll
  for (int j = 0; j < NW; ++j) {
    pBh[(size_t)c*NW + j] = pack_hi(v[2*j], v[2*j+1]);
    pBl[(size_t)c*NW + j] = pack_lo(v[2*j], v[2*j+1]);
  }
}

// partial products over 64-row chunks via MFMA (exact R9 structure)
__global__ __launch_bounds__(256, 4) void partial_mfma_kernel(
    const float* __restrict__ logsigs, const uint32_t* __restrict__ pBh,
    const uint32_t* __restrict__ pBl, float* __restrict__ ws_p) {
  const int hb = blockIdx.x;        // 0..3 (1024 cols each)
  const int chunk = blockIdx.y;     // 0..255
  const int tid = threadIdx.x;

  __shared__ __align__(16) uint32_t sAh[CR][APAD], sAl[CR][APAD];

  // convert this chunk's logsig rows (64 x 17) to packed bf16 hi/lo words
  const float* __restrict__ src = logsigs + (size_t)chunk*CR*CC;
  for (int e = tid; e < CR*NW; e += 256) {
    const int r = e >> 4, j = e & (NW-1);
    const int k0 = 2*j, k1 = k0 + 1;
    const float v0 = (k0 < CC) ? src[r*CC + k0] : 0.0f;
    const float v1 = (k1 < CC) ? src[r*CC + k1] : 0.0f;
    sAh[r][j] = pack_hi(v0, v1);
    sAl[r][j] = pack_lo(v0, v1);
  }
  __syncthreads();

  const int wv = tid >> 6, lane = tid & 63;
  const int g = lane >> 4, cr = lane & 15;

  short8 Ah[4], Al[4];
  #pragma unroll
  for (int mt = 0; mt < 4; ++mt) {
    const int r = mt*16 + cr;
    Ah[mt] = *reinterpret_cast<const short8*>(&sAh[r][4*g]);
    Al[mt] = *reinterpret_cast<const short8*>(&sAl[r][4*g]);
  }

  const int cbase = hb*1024 + wv*256;
  #pragma unroll 2
  for (int nt = 0; nt < 16; ++nt) {
    const int c = cbase + nt*16 + cr;
    const short8 Bh = *reinterpret_cast<const short8*>(&pBh[(size_t)c*NW + 4*g]);
    const short8 Bl = *reinterpret_cast<const short8*>(&pBl[(size_t)c*NW + 4*g]);
    float pcol = 1.0f;
    #pragma unroll
    for (int mt = 0; mt < 4; ++mt) {
      f32x4 acc = {0.0f, 0.0f, 0.0f, 0.0f};
      acc = __builtin_amdgcn_mfma_f32_16x16x32_bf16(Ah[mt], Bh, acc, 0, 0, 0);
      acc = __builtin_amdgcn_mfma_f32_16x16x32_bf16(Ah[mt], Bl, acc, 0, 0, 0);
      acc = __builtin_amdgcn_mfma_f32_16x16x32_bf16(Al[mt], Bh, acc, 0, 0, 0);
      pcol *= (1.0f + acc[0]) * (1.0f + acc[1]) * (1.0f + acc[2]) * (1.0f + acc[3]);
    }
    pcol *= __shfl_xor(pcol, 16, 64);
    pcol *= __shfl_xor(pcol, 32, 64);
    if (g == 0) ws_p[(size_t)chunk*HID + c] = pcol;
  }
}

// tailAB: per-h product over all chunks, y0, logits via atomicAdd,
// last block reads coherent logits + softmax.
__global__ __launch_bounds__(256) void tailAB_kernel(
    const float* __restrict__ ws_p, const float* __restrict__ Win,
    const float* __restrict__ bin,  const float* __restrict__ x0,
    const float* __restrict__ Wout, const float* __restrict__ bout,
    float* __restrict__ ws_logit, uint32_t* __restrict__ cnt,
    float* __restrict__ out) {
  const int b = blockIdx.x, tid = threadIdx.x;
  const int h0 = b * HPB;
  const int hh = tid & 15, sl = tid >> 4;

  __shared__ float sp[HPB][17];
  __shared__ float sy[HPB];
  __shared__ float slog[NLAB];
  __shared__ bool isLast;

  // slice product: thread (hh,sl) multiplies chunks sl*16..sl*16+15 for h0+hh
  {
    float p = 1.0f;
    #pragma unroll
    for (int i = 0; i < 16; ++i)
      p *= ws_p[(size_t)(sl*16 + i)*HID + h0 + hh];
    sp[hh][sl] = p;
  }
  __syncthreads();

  if (tid < HPB) {
    float P = 1.0f;
    #pragma unroll
    for (int s = 0; s < 16; ++s) P *= sp[tid][s];
    const int h = h0 + tid;
    const float4* __restrict__ wrow = reinterpret_cast<const float4*>(Win + (size_t)h*16);
    float y = bin[h];
    #pragma unroll
    for (int q = 0; q < 4; ++q) {
      float4 w = wrow[q];
      y = fmaf(w.x, x0[q*4+0], y);
      y = fmaf(w.y, x0[q*4+1], y);
      y = fmaf(w.z, x0[q*4+2], y);
      y = fmaf(w.w, x0[q*4+3], y);
    }
    sy[tid] = y * P;
  }
  __syncthreads();

  // partial logits for this block's 16 h -> device-scope atomic accumulate
  if (tid < NLAB*HPB) {                     // 160 threads
    const int j = tid >> 4, k = tid & 15;
    float v = Wout[(size_t)j*HID + h0 + k] * sy[k];
    v += __shfl_xor(v, 1, 64);
    v += __shfl_xor(v, 2, 64);
    v += __shfl_xor(v, 4, 64);
    v += __shfl_xor(v, 8, 64);
    if (k == 0) atomicAdd(&ws_logit[j], v);
  }
  // __syncthreads lowers with a vmcnt(0) drain -> this block's adds are
  // complete at the coherence point before the counter bump below.
  __syncthreads();
  if (tid == 0) isLast = (atomicAdd(cnt, 1u) == RBLK - 1);
  __syncthreads();
  if (!isLast) return;

  // last block: all 256 blocks' adds have completed (each preceded its
  // counter bump). Read via agent-scope atomic loads (coherent).
  if (tid < NLAB)
    slog[tid] = __hip_atomic_load(&ws_logit[tid], __ATOMIC_RELAXED,
                                  __HIP_MEMORY_SCOPE_AGENT) + bout[tid];
  __syncthreads();
  if (tid == 0) {
    float m = slog[0];
    #pragma unroll
    for (int j = 1; j < NLAB; ++j) m = fmaxf(m, slog[j]);
    float ssum = 0.0f;
    float e[NLAB];
    #pragma unroll
    for (int j = 0; j < NLAB; ++j) { e[j] = __expf(slog[j] - m); ssum += e[j]; }
    const float inv = 1.0f / ssum;
    #pragma unroll
    for (int j = 0; j < NLAB; ++j) out[j] = e[j] * inv;
  }
}

extern "C" void kernel_launch(void* const* d_in, const int* in_sizes, int n_in,
                              void* d_out, int out_size, void* d_ws, size_t ws_size,
                              hipStream_t stream) {
  // inputs: 0=ts (unused), 1=logsigs (L,C), 2=x0 (D), 3=W_in (H,D), 4=b_in (H),
  //         5=vf_A (C,H), 6=W_out (10,H), 7=b_out (10)
  const float* logsigs = (const float*)d_in[1];
  const float* x0      = (const float*)d_in[2];
  const float* Win     = (const float*)d_in[3];
  const float* bin     = (const float*)d_in[4];
  const float* vfA     = (const float*)d_in[5];
  const float* Wout    = (const float*)d_in[6];
  const float* bout    = (const float*)d_in[7];
  float* out = (float*)d_out;

  // workspace layout (16B-aligned slices)
  float*    ws_p     = (float*)d_ws;                            // 4MB
  uint32_t* pBh      = (uint32_t*)(ws_p + (size_t)NCHUNK*HID);  // 256KB
  uint32_t* pBl      = pBh + (size_t)HID*NW;                    // 256KB
  float*    ws_logit = (float*)(pBl + (size_t)HID*NW);          // 10 f32
  uint32_t* cnt      = (uint32_t*)(ws_logit + 16);

  pack_vfA_kernel<<<HID/256, 256, 0, stream>>>(vfA, pBh, pBl, ws_logit, cnt);
  partial_mfma_kernel<<<dim3(4, NCHUNK), 256, 0, stream>>>(logsigs, pBh, pBl, ws_p);
  tailAB_kernel<<<RBLK, 256, 0, stream>>>(ws_p, Win, bin, x0, Wout, bout,
                                          ws_logit, cnt, out);
}

// Round 13
// 23.348 us; speedup vs baseline: 1.5730x; 1.5730x over previous
//
#include <hip/hip_runtime.h>
#include <hip/hip_bf16.h>
#include <stdint.h>

// LogLinearCDE: out = softmax(W_out @ (y0 * prod_l flows[l]) + b_out)
// flows[l,h] = 1 + sum_c logsigs[l,c]*vf_A[c,h];  y0 = W_in@x0 + b_in
// R13: 3 kernels, no fences, no atomics. Partial uses 32x32x16 MFMA with
// B (vf_A) converted fp32->bf16 hi/lo ONCE per block into LDS (pack kernel
// eliminated; B global traffic 128MB -> 34MB). 2 chunks per block share the
// staged B. Exact hi/lo arithmetic: M1=Ah.Bh, M2=Ah.Bl, M3=Al.Bh (k0-15),
// M4 = 3-slot cleanup for k16. tailA/tailB identical to R9.

#define LSTEPS 16384
#define HID    4096
#define CC     17
#define NLAB   10
#define NCHUNK 256
#define CR     64          // rows per chunk
#define CPB    2           // chunks per block
#define COLS   512         // columns per block
#define HPB    16          // h per tailA block
#define RBLK   256         // tailA blocks

typedef __attribute__((ext_vector_type(8)))  short short8;
typedef __attribute__((ext_vector_type(16))) float f32x16;

static __device__ __forceinline__ unsigned short f2bf(float x) {
  __hip_bfloat16 h = __float2bfloat16(x);
  return *reinterpret_cast<unsigned short*>(&h);
}
static __device__ __forceinline__ float bf2f(unsigned short u) {
  __hip_bfloat16 h; *reinterpret_cast<unsigned short*>(&h) = u;
  return __bfloat162float(h);
}
static __device__ __forceinline__ uint32_t pk(unsigned short lo, unsigned short hi) {
  return (uint32_t)lo | ((uint32_t)hi << 16);
}

// partial products over 64-row chunks via 32x32x16 MFMA, CPB chunks/block.
__global__ __launch_bounds__(256, 2) void partial_mfma_kernel(
    const float* __restrict__ logsigs, const float* __restrict__ vfA,
    float* __restrict__ ws_p) {
  const int cb     = blockIdx.x;     // col-group 0..7 (512 cols each)
  const int cgroup = blockIdx.y;     // 0..127 (2 chunks each)
  const int chunk0 = cgroup * CPB;
  const int tid = threadIdx.x;

  // A: per chunk, [64 rows][16 k] bf16 hi/lo as 8 u32 words + k16 frag (4 w)
  __shared__ __align__(16) uint32_t sAh[CPB][CR][8], sAl[CPB][CR][8], sA4[CPB][CR][4];
  // B: [kh][512 cols][4 words] for hi and lo (k0-15), + k16 frag [512][4]
  __shared__ __align__(16) uint32_t sBh[2][COLS][4], sBl[2][COLS][4], sB4[COLS][4];

  // ---- stage A: 128 rows (2 chunks x 64), one row per thread (tid<128)
  if (tid < CPB*CR) {
    const int ch = tid >> 6, r = tid & 63;
    const float* __restrict__ row = logsigs + (size_t)(cgroup*CPB*CR + ch*CR + r)*CC;
    float ls[CC];
    #pragma unroll
    for (int k = 0; k < CC; ++k) ls[k] = row[k];
    #pragma unroll
    for (int j = 0; j < 8; ++j) {
      const unsigned short h0 = f2bf(ls[2*j]),   h1 = f2bf(ls[2*j+1]);
      const unsigned short l0 = f2bf(ls[2*j]   - bf2f(h0));
      const unsigned short l1 = f2bf(ls[2*j+1] - bf2f(h1));
      sAh[ch][r][j] = pk(h0, h1);
      sAl[ch][r][j] = pk(l0, l1);
    }
    const unsigned short a16h = f2bf(ls[16]);
    const unsigned short a16l = f2bf(ls[16] - bf2f(a16h));
    sA4[ch][r][0] = pk(a16h, a16h);   // slots 0,1 = Ah16, Ah16
    sA4[ch][r][1] = pk(a16l, 0);      // slot 2 = Al16
    sA4[ch][r][2] = 0;
    sA4[ch][r][3] = 0;
  }

  // ---- stage B: 512 cols, 2 rounds of 256 (coalesced across k)
  #pragma unroll
  for (int rd = 0; rd < 2; ++rd) {
    const int c  = rd*256 + tid;
    const int gc = cb*COLS + c;
    float v[CC];
    #pragma unroll
    for (int k = 0; k < CC; ++k) v[k] = vfA[(size_t)k*HID + gc];
    unsigned short bh[CC], bl[CC];
    #pragma unroll
    for (int k = 0; k < CC; ++k) {
      bh[k] = f2bf(v[k]);
      bl[k] = f2bf(v[k] - bf2f(bh[k]));
    }
    #pragma unroll
    for (int j = 0; j < 4; ++j) {
      sBh[0][c][j] = pk(bh[2*j],   bh[2*j+1]);     // k0-7
      sBh[1][c][j] = pk(bh[8+2*j], bh[9+2*j]);     // k8-15
      sBl[0][c][j] = pk(bl[2*j],   bl[2*j+1]);
      sBl[1][c][j] = pk(bl[8+2*j], bl[9+2*j]);
    }
    sB4[c][0] = pk(bh[16], bl[16]);   // slots 0,1 = Bh16, Bl16
    sB4[c][1] = pk(bh[16], 0);        // slot 2 = Bh16
    sB4[c][2] = 0;
    sB4[c][3] = 0;
  }
  __syncthreads();

  const int wv = tid >> 6, lane = tid & 63;
  const int cl = lane & 31, kh = lane >> 5;

  // A fragments (held in regs): per (chunk, row-tile)
  short8 Ah[CPB][2], Al[CPB][2], A4[CPB][2];
  #pragma unroll
  for (int ch = 0; ch < CPB; ++ch)
    #pragma unroll
    for (int rt = 0; rt < 2; ++rt) {
      const int r = rt*32 + cl;
      Ah[ch][rt] = *reinterpret_cast<const short8*>(&sAh[ch][r][kh*4]);
      Al[ch][rt] = *reinterpret_cast<const short8*>(&sAl[ch][r][kh*4]);
      short8 z = {0,0,0,0,0,0,0,0};
      if (kh == 0) z = *reinterpret_cast<const short8*>(&sA4[ch][r][0]);
      A4[ch][rt] = z;
    }

  const int wcol0 = wv * 128;       // wave covers 128 cols = 4 col-tiles
  for (int ct = 0; ct < 4; ++ct) {
    const int c = wcol0 + ct*32 + cl;
    const short8 Bh = *reinterpret_cast<const short8*>(&sBh[kh][c][0]);
    const short8 Bl = *reinterpret_cast<const short8*>(&sBl[kh][c][0]);
    short8 B4 = {0,0,0,0,0,0,0,0};
    if (kh == 0) B4 = *reinterpret_cast<const short8*>(&sB4[c][0]);

    #pragma unroll
    for (int ch = 0; ch < CPB; ++ch) {
      f32x16 acc = {};
      #pragma unroll
      for (int rt = 0; rt < 2; ++rt) {
        f32x16 a = {};
        a = __builtin_amdgcn_mfma_f32_32x32x16_bf16(Ah[ch][rt], Bh, a, 0, 0, 0);
        a = __builtin_amdgcn_mfma_f32_32x32x16_bf16(Ah[ch][rt], Bl, a, 0, 0, 0);
        a = __builtin_amdgcn_mfma_f32_32x32x16_bf16(Al[ch][rt], Bh, a, 0, 0, 0);
        a = __builtin_amdgcn_mfma_f32_32x32x16_bf16(A4[ch][rt], B4, a, 0, 0, 0);
        if (rt == 0) acc = a;
        else {
          // combine: product of (1+S) over both row-tiles, elementwise first
          #pragma unroll
          for (int i = 0; i < 16; ++i) acc[i] = (1.0f + acc[i]) * (1.0f + a[i]);
        }
      }
      // acc[i] now = (1+S_rt0[i])*(1+S_rt1[i]); product over 16 regs
      float p = acc[0];
      #pragma unroll
      for (int i = 1; i < 16; ++i) p *= acc[i];
      // partner lane (lane^32) holds the other 16 rows of the same column
      p *= __shfl_xor(p, 32, 64);
      if (kh == 0)
        ws_p[(size_t)(chunk0+ch)*HID + cb*COLS + c] = p;
    }
  }
}

// tailA: per-h product over all chunks, y0, per-block partial logits (R9).
__global__ __launch_bounds__(256) void tailA_kernel(
    const float* __restrict__ ws_p, const float* __restrict__ Win,
    const float* __restrict__ bin,  const float* __restrict__ x0,
    const float* __restrict__ Wout, float* __restrict__ ws_lp) {
  const int b = blockIdx.x, tid = threadIdx.x;
  const int h0 = b * HPB;
  const int hh = tid & 15, sl = tid >> 4;

  __shared__ float sp[HPB][17];
  __shared__ float sy[HPB];

  {
    float p = 1.0f;
    #pragma unroll
    for (int i = 0; i < 16; ++i)
      p *= ws_p[(size_t)(sl*16 + i)*HID + h0 + hh];
    sp[hh][sl] = p;
  }
  __syncthreads();

  if (tid < HPB) {
    float P = 1.0f;
    #pragma unroll
    for (int s = 0; s < 16; ++s) P *= sp[tid][s];
    const int h = h0 + tid;
    const float4* __restrict__ wrow = reinterpret_cast<const float4*>(Win + (size_t)h*16);
    float y = bin[h];
    #pragma unroll
    for (int q = 0; q < 4; ++q) {
      float4 w = wrow[q];
      y = fmaf(w.x, x0[q*4+0], y);
      y = fmaf(w.y, x0[q*4+1], y);
      y = fmaf(w.z, x0[q*4+2], y);
      y = fmaf(w.w, x0[q*4+3], y);
    }
    sy[tid] = y * P;
  }
  __syncthreads();

  if (tid < NLAB*HPB) {                     // 160 threads
    const int j = tid >> 4, k = tid & 15;
    float v = Wout[(size_t)j*HID + h0 + k] * sy[k];
    v += __shfl_xor(v, 1, 64);
    v += __shfl_xor(v, 2, 64);
    v += __shfl_xor(v, 4, 64);
    v += __shfl_xor(v, 8, 64);
    if (k == 0) ws_lp[b*16 + j] = v;
  }
}

// tailB: one block sums 256x10 partial logits (deterministic order) + softmax
__global__ __launch_bounds__(256) void tailB_kernel(
    const float* __restrict__ ws_lp, const float* __restrict__ bout,
    float* __restrict__ out) {
  const int tid = threadIdx.x;
  __shared__ float slog[NLAB];

  if (tid < NLAB*16) {                      // j x 16 block-slices
    const int j = tid >> 4, s = tid & 15;
    float acc = 0.0f;
    #pragma unroll
    for (int bb = 0; bb < 16; ++bb)
      acc += ws_lp[(s*16 + bb)*16 + j];
    acc += __shfl_xor(acc, 1, 64);
    acc += __shfl_xor(acc, 2, 64);
    acc += __shfl_xor(acc, 4, 64);
    acc += __shfl_xor(acc, 8, 64);
    if (s == 0) slog[j] = acc + bout[j];
  }
  __syncthreads();
  if (tid == 0) {
    float m = slog[0];
    #pragma unroll
    for (int j = 1; j < NLAB; ++j) m = fmaxf(m, slog[j]);
    float ssum = 0.0f;
    float e[NLAB];
    #pragma unroll
    for (int j = 0; j < NLAB; ++j) { e[j] = __expf(slog[j] - m); ssum += e[j]; }
    const float inv = 1.0f / ssum;
    #pragma unroll
    for (int j = 0; j < NLAB; ++j) out[j] = e[j] * inv;
  }
}

extern "C" void kernel_launch(void* const* d_in, const int* in_sizes, int n_in,
                              void* d_out, int out_size, void* d_ws, size_t ws_size,
                              hipStream_t stream) {
  // inputs: 0=ts (unused), 1=logsigs (L,C), 2=x0 (D), 3=W_in (H,D), 4=b_in (H),
  //         5=vf_A (C,H), 6=W_out (10,H), 7=b_out (10)
  const float* logsigs = (const float*)d_in[1];
  const float* x0      = (const float*)d_in[2];
  const float* Win     = (const float*)d_in[3];
  const float* bin     = (const float*)d_in[4];
  const float* vfA     = (const float*)d_in[5];
  const float* Wout    = (const float*)d_in[6];
  const float* bout    = (const float*)d_in[7];
  float* out = (float*)d_out;

  float* ws_p  = (float*)d_ws;                         // 256*4096 f32 = 4MB
  float* ws_lp = ws_p + (size_t)NCHUNK*HID;            // RBLK*16 f32

  partial_mfma_kernel<<<dim3(HID/COLS, NCHUNK/CPB), 256, 0, stream>>>(logsigs, vfA, ws_p);
  tailA_kernel<<<RBLK, 256, 0, stream>>>(ws_p, Win, bin, x0, Wout, ws_lp);
  tailB_kernel<<<1, 256, 0, stream>>>(ws_lp, bout, out);
}

// Round 14
// 18.020 us; speedup vs baseline: 2.0381x; 1.2957x over previous
//
#include <hip/hip_runtime.h>
#include <hip/hip_bf16.h>
#include <stdint.h>

// LogLinearCDE: out = softmax(W_out @ (y0 * prod_l flows[l]) + b_out)
// flows[l,h] = 1 + sum_c logsigs[l,c]*vf_A[c,h];  y0 = W_in@x0 + b_in
// R14: 3 kernels (R13 structure). Partial switches bf16-hi/lo (4 MFMA) ->
// single fp16 (2 MFMA: k0-15 main + k16 cleanup). f16's 2^-12 ulp gives
// ~6e-4 relative P error over L=16384 (30x under threshold). CR=128 rows
// per chunk merged in-register -> ws_p halves to 2MB. LDS 30KB, 4 blk/CU.

#define LSTEPS 16384
#define HID    4096
#define CC     17
#define NLAB   10
#define NCHUNK 128
#define CR     128         // rows per chunk (4 row-tiles of 32)
#define COLS   512         // columns per block
#define HPB    16          // h per tailA block
#define RBLK   256         // tailA blocks

typedef __attribute__((ext_vector_type(8)))  _Float16 half8;
typedef __attribute__((ext_vector_type(8)))  short short8;
typedef __attribute__((ext_vector_type(16))) float f32x16;

static __device__ __forceinline__ unsigned short f2h(float x) {
  _Float16 h = (_Float16)x;
  return *reinterpret_cast<unsigned short*>(&h);
}
static __device__ __forceinline__ uint32_t pk(unsigned short lo, unsigned short hi) {
  return (uint32_t)lo | ((uint32_t)hi << 16);
}

// partial products over 128-row chunks via 32x32x16_f16 MFMA.
__global__ __launch_bounds__(256, 4) void partial_mfma_kernel(
    const float* __restrict__ logsigs, const float* __restrict__ vfA,
    float* __restrict__ ws_p) {
  const int cb    = blockIdx.x;      // col-group 0..7 (512 cols each)
  const int chunk = blockIdx.y;      // 0..127
  const int tid = threadIdx.x;

  // A: [128 rows][8 words] f16 pairs (k0-15) + k16 frag [128][4 words]
  __shared__ __align__(16) uint32_t sA[CR][8], sA4[CR][4];
  // B: [kh][512 cols][4 words] (k0-7 / k8-15) + k16 frag [512][4 words]
  __shared__ __align__(16) uint32_t sB[2][COLS][4], sB4[COLS][4];

  // ---- stage A: one row per thread (tid < 128)
  if (tid < CR) {
    const int r = tid;
    const float* __restrict__ row = logsigs + (size_t)(chunk*CR + r)*CC;
    float ls[CC];
    #pragma unroll
    for (int k = 0; k < CC; ++k) ls[k] = row[k];
    #pragma unroll
    for (int j = 0; j < 8; ++j)
      sA[r][j] = pk(f2h(ls[2*j]), f2h(ls[2*j+1]));
    sA4[r][0] = pk(f2h(ls[16]), 0);
    sA4[r][1] = 0; sA4[r][2] = 0; sA4[r][3] = 0;
  }

  // ---- stage B: 512 cols in 2 rounds of 256 (coalesced per k)
  #pragma unroll
  for (int rd = 0; rd < 2; ++rd) {
    const int c  = rd*256 + tid;
    const int gc = cb*COLS + c;
    float v[CC];
    #pragma unroll
    for (int k = 0; k < CC; ++k) v[k] = vfA[(size_t)k*HID + gc];
    #pragma unroll
    for (int j = 0; j < 4; ++j) {
      sB[0][c][j] = pk(f2h(v[2*j]),   f2h(v[2*j+1]));   // k0-7
      sB[1][c][j] = pk(f2h(v[8+2*j]), f2h(v[9+2*j]));   // k8-15
    }
    sB4[c][0] = pk(f2h(v[16]), 0);
    sB4[c][1] = 0; sB4[c][2] = 0; sB4[c][3] = 0;
  }
  __syncthreads();

  const int wv = tid >> 6, lane = tid & 63;
  const int cl = lane & 31, kh = lane >> 5;

  // A fragments in regs: 4 row-tiles
  half8 Am[4], A4[4];
  #pragma unroll
  for (int rt = 0; rt < 4; ++rt) {
    const int r = rt*32 + cl;
    Am[rt] = __builtin_bit_cast(half8,
               *reinterpret_cast<const short8*>(&sA[r][kh*4]));
    short8 z = {0,0,0,0,0,0,0,0};
    if (kh == 0) z = *reinterpret_cast<const short8*>(&sA4[r][0]);
    A4[rt] = __builtin_bit_cast(half8, z);
  }

  const int wcol0 = wv * 128;        // wave covers 128 cols = 4 col-tiles
  #pragma unroll
  for (int ct = 0; ct < 4; ++ct) {
    const int c = wcol0 + ct*32 + cl;
    const half8 Bm = __builtin_bit_cast(half8,
                       *reinterpret_cast<const short8*>(&sB[kh][c][0]));
    short8 zb = {0,0,0,0,0,0,0,0};
    if (kh == 0) zb = *reinterpret_cast<const short8*>(&sB4[c][0]);
    const half8 B4 = __builtin_bit_cast(half8, zb);

    float p = 1.0f;
    #pragma unroll
    for (int rt = 0; rt < 4; ++rt) {
      f32x16 acc = {};
      acc = __builtin_amdgcn_mfma_f32_32x32x16_f16(Am[rt], Bm, acc, 0, 0, 0);
      acc = __builtin_amdgcn_mfma_f32_32x32x16_f16(A4[rt], B4, acc, 0, 0, 0);
      #pragma unroll
      for (int i = 0; i < 16; ++i) p *= (1.0f + acc[i]);
    }
    // partner lane (lane^32) holds the other 16 rows of each 32-row tile
    p *= __shfl_xor(p, 32, 64);
    if (kh == 0)
      ws_p[(size_t)chunk*HID + cb*COLS + c] = p;
  }
}

// tailA: per-h product over all chunks, y0, per-block partial logits.
__global__ __launch_bounds__(256) void tailA_kernel(
    const float* __restrict__ ws_p, const float* __restrict__ Win,
    const float* __restrict__ bin,  const float* __restrict__ x0,
    const float* __restrict__ Wout, float* __restrict__ ws_lp) {
  const int b = blockIdx.x, tid = threadIdx.x;
  const int h0 = b * HPB;
  const int hh = tid & 15, sl = tid >> 4;

  __shared__ float sp[HPB][17];
  __shared__ float sy[HPB];

  // slice product: thread (hh,sl) multiplies chunks sl*8..sl*8+7 for h0+hh
  {
    float p = 1.0f;
    #pragma unroll
    for (int i = 0; i < 8; ++i)
      p *= ws_p[(size_t)(sl*8 + i)*HID + h0 + hh];
    sp[hh][sl] = p;
  }
  __syncthreads();

  if (tid < HPB) {
    float P = 1.0f;
    #pragma unroll
    for (int s = 0; s < 16; ++s) P *= sp[tid][s];
    const int h = h0 + tid;
    const float4* __restrict__ wrow = reinterpret_cast<const float4*>(Win + (size_t)h*16);
    float y = bin[h];
    #pragma unroll
    for (int q = 0; q < 4; ++q) {
      float4 w = wrow[q];
      y = fmaf(w.x, x0[q*4+0], y);
      y = fmaf(w.y, x0[q*4+1], y);
      y = fmaf(w.z, x0[q*4+2], y);
      y = fmaf(w.w, x0[q*4+3], y);
    }
    sy[tid] = y * P;
  }
  __syncthreads();

  if (tid < NLAB*HPB) {                     // 160 threads
    const int j = tid >> 4, k = tid & 15;
    float v = Wout[(size_t)j*HID + h0 + k] * sy[k];
    v += __shfl_xor(v, 1, 64);
    v += __shfl_xor(v, 2, 64);
    v += __shfl_xor(v, 4, 64);
    v += __shfl_xor(v, 8, 64);
    if (k == 0) ws_lp[b*16 + j] = v;
  }
}

// tailB: one block sums 256x10 partial logits (deterministic order) + softmax
__global__ __launch_bounds__(256) void tailB_kernel(
    const float* __restrict__ ws_lp, const float* __restrict__ bout,
    float* __restrict__ out) {
  const int tid = threadIdx.x;
  __shared__ float slog[NLAB];

  if (tid < NLAB*16) {                      // j x 16 block-slices
    const int j = tid >> 4, s = tid & 15;
    float acc = 0.0f;
    #pragma unroll
    for (int bb = 0; bb < 16; ++bb)
      acc += ws_lp[(s*16 + bb)*16 + j];
    acc += __shfl_xor(acc, 1, 64);
    acc += __shfl_xor(acc, 2, 64);
    acc += __shfl_xor(acc, 4, 64);
    acc += __shfl_xor(acc, 8, 64);
    if (s == 0) slog[j] = acc + bout[j];
  }
  __syncthreads();
  if (tid == 0) {
    float m = slog[0];
    #pragma unroll
    for (int j = 1; j < NLAB; ++j) m = fmaxf(m, slog[j]);
    float ssum = 0.0f;
    float e[NLAB];
    #pragma unroll
    for (int j = 0; j < NLAB; ++j) { e[j] = __expf(slog[j] - m); ssum += e[j]; }
    const float inv = 1.0f / ssum;
    #pragma unroll
    for (int j = 0; j < NLAB; ++j) out[j] = e[j] * inv;
  }
}

extern "C" void kernel_launch(void* const* d_in, const int* in_sizes, int n_in,
                              void* d_out, int out_size, void* d_ws, size_t ws_size,
                              hipStream_t stream) {
  // inputs: 0=ts (unused), 1=logsigs (L,C), 2=x0 (D), 3=W_in (H,D), 4=b_in (H),
  //         5=vf_A (C,H), 6=W_out (10,H), 7=b_out (10)
  const float* logsigs = (const float*)d_in[1];
  const float* x0      = (const float*)d_in[2];
  const float* Win     = (const float*)d_in[3];
  const float* bin     = (const float*)d_in[4];
  const float* vfA     = (const float*)d_in[5];
  const float* Wout    = (const float*)d_in[6];
  const float* bout    = (const float*)d_in[7];
  float* out = (float*)d_out;

  float* ws_p  = (float*)d_ws;                         // 128*4096 f32 = 2MB
  float* ws_lp = ws_p + (size_t)NCHUNK*HID;            // RBLK*16 f32

  partial_mfma_kernel<<<dim3(HID/COLS, NCHUNK), 256, 0, stream>>>(logsigs, vfA, ws_p);
  tailA_kernel<<<RBLK, 256, 0, stream>>>(ws_p, Win, bin, x0, Wout, ws_lp);
  tailB_kernel<<<1, 256, 0, stream>>>(ws_lp, bout, out);
}